// Round 5
// baseline (182.117 us; speedup 1.0000x reference)
//
#include <hip/hip_runtime.h>
#include <math.h>
#include <float.h>

#define NB 4096
#define ND 256
#define NK 25
#define EPSF 1e-8f
#define CAP 256          // per-wave candidate capacity
#define CTGT 160         // bisection target count

typedef __attribute__((ext_vector_type(8))) short bf16x8;
typedef __attribute__((ext_vector_type(4))) float f32x4;

#define GLD_LDS16(gp, lp)                                                   \
    __builtin_amdgcn_global_load_lds(                                       \
        (const __attribute__((address_space(1))) void*)(uintptr_t)(gp),     \
        (__attribute__((address_space(3))) void*)(uint32_t)(uintptr_t)(lp), \
        16, 0, 0)

__device__ inline short f2bf(float x) {
    unsigned u = __float_as_uint(x);
    return (short)((u + 0x7FFF + ((u >> 16) & 1)) >> 16);
}
__device__ inline float bf2f(short s) {
    return __uint_as_float(((unsigned)(unsigned short)s) << 16);
}

// ---------------------------------------------------------------- prep: hi/lo bf16 split + ||f||^2
__global__ __launch_bounds__(64) void prep_kernel(const float* __restrict__ f,
                                                  short* __restrict__ fhl,
                                                  float* __restrict__ sq) {
    int row  = blockIdx.x;
    int lane = threadIdx.x;
    float4 v = ((const float4*)(f + (size_t)row * ND))[lane];
    float acc = v.x * v.x + v.y * v.y + v.z * v.z + v.w * v.w;
    float vv[4] = {v.x, v.y, v.z, v.w};
    short h[4], l[4];
#pragma unroll
    for (int e = 0; e < 4; ++e) {
        h[e] = f2bf(vv[e]);
        l[e] = f2bf(vv[e] - bf2f(h[e]));
    }
    *(short4*)(fhl + (size_t)row * 512 + lane * 4)       = make_short4(h[0], h[1], h[2], h[3]);
    *(short4*)(fhl + (size_t)row * 512 + 256 + lane * 4) = make_short4(l[0], l[1], l[2], l[3]);
#pragma unroll
    for (int off = 32; off; off >>= 1) acc += __shfl_down(acc, off);
    if (lane == 0) sq[row] = acc;
}

// ---------------------------------------------------------------- MFMA Gram + dist epilogue
#define BM 128
#define BK 64
__global__ __launch_bounds__(256) void gram_kernel(const short* __restrict__ fhl,
                                                   const float* __restrict__ sq,
                                                   float* __restrict__ dist) {
    __shared__ __align__(16) short As[BM * BK];
    __shared__ __align__(16) short Bs[BM * BK];
    int b   = blockIdx.x;
    int ti  = (b >> 5) * BM;
    int tj  = (b & 31) * BM;
    int tid = threadIdx.x;
    int w = tid >> 6, lane = tid & 63;
    int wr = w >> 1, wc = w & 1;
    int fr = lane & 15, fq = lane >> 4;

    f32x4 acc[4][4];
#pragma unroll
    for (int m = 0; m < 4; ++m)
#pragma unroll
        for (int n = 0; n < 4; ++n) acc[m][n] = (f32x4){0.f, 0.f, 0.f, 0.f};

    int srow = lane >> 3;
    int scol = (lane & 7) * 8;

    for (int s = 0; s < 12; ++s) {
        int k0 = s * 64;
        int kA = (k0 < 512) ? (k0 & 255) : (k0 - 256);   // h,h,l
        int kB = (k0 < 512) ? k0 : (k0 - 512);           // h,l,h
#pragma unroll
        for (int i = 0; i < 4; ++i) {
            int c   = 4 * w + i;
            int row = c * 8 + srow;
            GLD_LDS16(fhl + (size_t)(ti + row) * 512 + kA + scol, As + c * 512);
            GLD_LDS16(fhl + (size_t)(tj + row) * 512 + kB + scol, Bs + c * 512);
        }
        __syncthreads();
#pragma unroll
        for (int kk = 0; kk < 2; ++kk) {
            bf16x8 af[4], bfr[4];
#pragma unroll
            for (int m = 0; m < 4; ++m)
                af[m] = *(const bf16x8*)(As + (wr * 64 + m * 16 + fr) * 64 + kk * 32 + fq * 8);
#pragma unroll
            for (int n = 0; n < 4; ++n)
                bfr[n] = *(const bf16x8*)(Bs + (wc * 64 + n * 16 + fr) * 64 + kk * 32 + fq * 8);
#pragma unroll
            for (int m = 0; m < 4; ++m)
#pragma unroll
                for (int n = 0; n < 4; ++n)
                    acc[m][n] = __builtin_amdgcn_mfma_f32_16x16x32_bf16(af[m], bfr[n], acc[m][n], 0, 0, 0);
        }
        __syncthreads();
    }

#pragma unroll
    for (int m = 0; m < 4; ++m) {
#pragma unroll
        for (int j = 0; j < 4; ++j) {
            int gi = ti + wr * 64 + m * 16 + fq * 4 + j;
            float si = sq[gi];
            float* drow = dist + (size_t)gi * NB + tj + wc * 64;
#pragma unroll
            for (int n = 0; n < 4; ++n) {
                float d = si + sq[tj + wc * 64 + n * 16 + fr] - 2.f * acc[m][n][j];
                drow[n * 16 + fr] = fmaxf(d, 0.f);
            }
        }
    }
}

// ---------------------------------------------------------------- wave-per-row top-25 (no barriers)
__global__ __launch_bounds__(256) void topk3_kernel(const float* __restrict__ dist,
                                                    int* __restrict__ idxk,
                                                    float* __restrict__ dk,
                                                    float* __restrict__ sigma) {
    int wid  = threadIdx.x >> 6;
    int lane = threadIdx.x & 63;
    int row  = blockIdx.x * 4 + wid;
    __shared__ float cval[4][CAP];
    __shared__ int   cidx[4][CAP];

    float v[64];
    const float4* src = (const float4*)(dist + (size_t)row * NB);
#pragma unroll
    for (int c = 0; c < 16; ++c) {
        float4 q = src[c * 64 + lane];
        v[c * 4 + 0] = q.x; v[c * 4 + 1] = q.y;
        v[c * 4 + 2] = q.z; v[c * 4 + 3] = q.w;
    }

    float mx = v[0];
#pragma unroll
    for (int e = 1; e < 64; ++e) mx = fmaxf(mx, v[e]);
#pragma unroll
    for (int off = 32; off; off >>= 1) mx = fmaxf(mx, __shfl_xor(mx, off));

    unsigned lo = 0u, hi = __float_as_uint(mx) + 1u;
    int cnt_hi = NB;
    for (int it = 0; it < 40; ++it) {
        if (cnt_hi <= CTGT || hi <= lo + 1u) break;
        unsigned mid = (lo + hi) >> 1;
        float T = __uint_as_float(mid);
        int c = 0;
#pragma unroll
        for (int e = 0; e < 64; ++e) c += (v[e] < T) ? 1 : 0;
#pragma unroll
        for (int off = 32; off; off >>= 1) c += __shfl_xor(c, off);
        if (c >= NK) { hi = mid; cnt_hi = c; } else { lo = mid; }
    }

    float Thi = __uint_as_float(hi);
    unsigned long long ltmask = (1ull << lane) - 1ull;
    int cnt = 0;
#pragma unroll
    for (int e = 0; e < 64; ++e) {
        bool p = (v[e] < Thi);
        unsigned long long m = __ballot(p);
        if (p) {
            int pos = cnt + __popcll(m & ltmask);
            if (pos < CAP) {
                cval[wid][pos] = v[e];
                cidx[wid][pos] = ((e >> 2) * 64 + lane) * 4 + (e & 3);
            }
        }
        cnt += __popcll(m);
    }
    cnt = min(cnt, CAP);

    float ssum = 0.f;
    for (int it = 0; it < NK; ++it) {
        float bv = FLT_MAX; int bi = NB; int bp = -1;
        for (int r = lane; r < cnt; r += 64) {
            float cv = cval[wid][r]; int ci = cidx[wid][r];
            if (cv < bv || (cv == bv && ci < bi)) { bv = cv; bi = ci; bp = r; }
        }
#pragma unroll
        for (int off = 32; off; off >>= 1) {
            float ov = __shfl_xor(bv, off);
            int   oi = __shfl_xor(bi, off);
            int   op = __shfl_xor(bp, off);
            if (ov < bv || (ov == bv && oi < bi)) { bv = ov; bi = oi; bp = op; }
        }
        if (lane == 0) {
            idxk[row * NK + it] = bi;
            dk[row * NK + it]   = bv;
            cval[wid][bp] = FLT_MAX;
        }
        ssum += sqrtf(bv + EPSF);
    }
    if (lane == 0) sigma[row] = ssum * (1.0f / NK);
}

// ---------------------------------------------------------------- P rows + score-sorted prefix tables
// bs[q][0..24] = neighbor scores sorted asc (pad 25..31 = FLT_MAX)
// cs[q][pos]   = (C,S): exclusive prefix of (P, P*s) over sorted order, pos in 0..25
// => G_q(x) = sum_r P[q][r]*relu(x - s_qr) = x*C[pos] - S[pos], pos = #(scores < x)
__global__ __launch_bounds__(64) void buildp_kernel(const int* __restrict__ idxk,
                                                    const float* __restrict__ dk,
                                                    const float* __restrict__ sigma,
                                                    const int* __restrict__ labels,
                                                    const float* __restrict__ scores,
                                                    float* __restrict__ pval,
                                                    float* __restrict__ bs,
                                                    float2* __restrict__ cs) {
    int row  = blockIdx.x;
    int lane = threadIdx.x;
    __shared__ float sb[32];
    __shared__ float sp[32];

    float w = 0.f;
    int j = 0;
    if (lane < NK) {
        j = idxk[row * NK + lane];
        bool mut = false;
        for (int n = 0; n < NK; ++n) mut |= (idxk[j * NK + n] == row);
        bool dir = labels[row] <= labels[j];
        float sij = sigma[row] * sigma[j] + EPSF;
        w = (mut && dir) ? expf(-dk[row * NK + lane] / sij) : 0.f;
        if (j == row) w += 1.f;
    }
    float rs = w;
#pragma unroll
    for (int off = 32; off; off >>= 1) rs += __shfl_down(rs, off);
    rs = __shfl(rs, 0);
    float pv = (lane < NK) ? w / (rs + EPSF) : 0.f;
    if (lane < NK) pval[row * NK + lane] = pv;

    // stable rank of neighbor score among the 25
    float sj = (lane < NK) ? scores[j] : FLT_MAX;
    int rank = 0;
#pragma unroll
    for (int u = 0; u < NK; ++u) {
        float su = __shfl(sj, u);
        rank += (su < sj || (su == sj && u < lane)) ? 1 : 0;
    }
    if (lane < 32) { sb[lane] = FLT_MAX; sp[lane] = 0.f; }
    __syncthreads();
    if (lane < NK) { sb[rank] = sj; sp[rank] = pv; }
    __syncthreads();

    float b = sb[lane & 31];
    float p = sp[lane & 31];
    float c  = p;
    float s2 = p * b;                            // pad: 0 * FLT_MAX = 0
#pragma unroll
    for (int off = 1; off < 32; off <<= 1) {
        float oc = __shfl_up(c, off);
        float os = __shfl_up(s2, off);
        if (lane >= off) { c += oc; s2 += os; }
    }
    float ce = __shfl_up(c, 1);                  // exclusive
    float se = __shfl_up(s2, 1);
    if (lane == 0) { ce = 0.f; se = 0.f; }
    if (lane < 32) {
        bs[row * 32 + lane] = b;
        cs[row * 32 + lane] = make_float2(ce, se);
    }
}

// ---------------------------------------------------------------- init out
__global__ void init_kernel(float* __restrict__ out) { out[0] = 0.f; }

// ---------------------------------------------------------------- G-table eval
__device__ inline float geval(const float* __restrict__ bs,
                              const float2* __restrict__ cs,
                              int q, float si) {
    const float4* b4 = (const float4*)(bs + q * 32);
    int pos = 0;
#pragma unroll
    for (int t = 0; t < 7; ++t) {                // 28 floats (25 + FLT_MAX pads)
        float4 v = b4[t];
        pos += (v.x < si) + (v.y < si) + (v.z < si) + (v.w < si);
    }
    float2 c = cs[q * 32 + pos];
    return si * c.x - c.y;
}

// ---------------------------------------------------------------- sparse 3-hop loss via G-tables
__global__ __launch_bounds__(256) void loss_kernel(const float* __restrict__ scores,
                                                   const int* __restrict__ idxk,
                                                   const float* __restrict__ pval,
                                                   const float* __restrict__ bs,
                                                   const float2* __restrict__ cs,
                                                   float* __restrict__ out) {
    int i   = blockIdx.x;
    int tid = threadIdx.x;
    __shared__ int   sh_j[NK];
    __shared__ float sh_p[NK];
    __shared__ float red[4];
    float si = scores[i];
    if (tid < NK) { sh_j[tid] = idxk[i * NK + tid]; sh_p[tid] = pval[i * NK + tid]; }
    __syncthreads();

    float acc = 0.f;
    // t=1 (direct) + t=2 (one G-eval per 1-hop neighbor)
    if (tid < NK) {
        int j = sh_j[tid]; float p = sh_p[tid];
        acc += p * fmaxf(si - scores[j], 0.f);
        acc += 0.5f * p * geval(bs, cs, j, si);
    }
    // t=3: one G-eval per 2-hop pair
    for (int pair = tid; pair < NK * NK; pair += 256) {
        int m = pair / NK, n = pair - m * NK;
        int jm = sh_j[m];
        float pp = sh_p[m] * pval[jm * NK + n] * (1.f / 3.f);
        int q = idxk[jm * NK + n];
        acc += pp * geval(bs, cs, q, si);
    }
#pragma unroll
    for (int off = 32; off; off >>= 1) acc += __shfl_down(acc, off);
    if ((tid & 63) == 0) red[tid >> 6] = acc;
    __syncthreads();
    if (tid == 0) atomicAdd(out, (red[0] + red[1] + red[2] + red[3]) * (1.0f / NB));
}

// ---------------------------------------------------------------- launch
extern "C" void kernel_launch(void* const* d_in, const int* in_sizes, int n_in,
                              void* d_out, int out_size, void* d_ws, size_t ws_size,
                              hipStream_t stream) {
    const float* features = (const float*)d_in[0];
    const float* scores   = (const float*)d_in[1];
    const int*   labels   = (const int*)d_in[2];
    float* out = (float*)d_out;

    char* ws = (char*)d_ws;
    size_t off = 0;
    float*  dist  = (float*) (ws + off); off += (size_t)NB * NB * 4;
    short*  fhl   = (short*) (ws + off); off += (size_t)NB * 512 * 2;
    float*  sq    = (float*) (ws + off); off += (size_t)NB * 4;
    int*    idxk  = (int*)   (ws + off); off += (size_t)NB * NK * 4;
    float*  dk    = (float*) (ws + off); off += (size_t)NB * NK * 4;
    float*  sigma = (float*) (ws + off); off += (size_t)NB * 4;
    float*  pval  = (float*) (ws + off); off += (size_t)NB * NK * 4;
    float*  bs    = (float*) (ws + off); off += (size_t)NB * 32 * 4;
    float2* cs    = (float2*)(ws + off); off += (size_t)NB * 32 * 8;

    init_kernel<<<1, 1, 0, stream>>>(out);
    prep_kernel<<<NB, 64, 0, stream>>>(features, fhl, sq);
    gram_kernel<<<(NB / BM) * (NB / BM), 256, 0, stream>>>(fhl, sq, dist);
    topk3_kernel<<<NB / 4, 256, 0, stream>>>(dist, idxk, dk, sigma);
    buildp_kernel<<<NB, 64, 0, stream>>>(idxk, dk, sigma, labels, scores, pval, bs, cs);
    loss_kernel<<<NB, 256, 0, stream>>>(scores, idxk, pval, bs, cs, out);
}